// Round 1
// baseline (289.962 us; speedup 1.0000x reference)
//
#include <hip/hip_runtime.h>

// Problem: classical Gram-Schmidt over 16 vectors of dim 256, for 32768
// independent rows, fp32. Input/output layout: (16, 32768, 256) flat.
//
// Mapping: one wave64 per row. Lane l owns elements [4l, 4l+4) of every
// vector as a float4 -> 16 float4 = 64 VGPRs of live state per lane.
// Dot products: 4 lane-local FMAs + 6-step shfl_xor butterfly (result in
// all lanes). No LDS, no atomics. Memory-bound target ~1.07 GB traffic.

constexpr int NM = 16;      // models / vectors per row
constexpr int NR = 32768;   // rows
constexpr int D4 = 64;      // 256 / 4 floats per lane

__device__ __forceinline__ float wave_sum64(float s) {
    s += __shfl_xor(s, 1, 64);
    s += __shfl_xor(s, 2, 64);
    s += __shfl_xor(s, 4, 64);
    s += __shfl_xor(s, 8, 64);
    s += __shfl_xor(s, 16, 64);
    s += __shfl_xor(s, 32, 64);
    return s;
}

__device__ __forceinline__ float dot4(const float4& a, const float4& b) {
    return a.x * b.x + a.y * b.y + a.z * b.z + a.w * b.w;
}

__global__ __launch_bounds__(256) void gs_kernel(const float* __restrict__ x,
                                                 float* __restrict__ out) {
    const int lane = threadIdx.x & 63;
    const int wid  = threadIdx.x >> 6;
    const int row  = blockIdx.x * 4 + wid;
    if (row >= NR) return;

    const float4* __restrict__ xi = reinterpret_cast<const float4*>(x);
    float4* __restrict__ oo       = reinterpret_cast<float4*>(out);

    // Load the 16 vectors for this row (coalesced: 64 lanes x 16B = 1 KB/inst).
    float4 v[NM];
#pragma unroll
    for (int i = 0; i < NM; ++i) {
        v[i] = xi[(size_t)(i * NR + row) * D4 + lane];
    }

    // Normalize v[0] (safe-div: zero if norm == 0).
    {
        float s   = wave_sum64(dot4(v[0], v[0]));
        float inv = (s > 0.0f) ? rsqrtf(s) : 0.0f;
        v[0].x *= inv; v[0].y *= inv; v[0].z *= inv; v[0].w *= inv;
    }

    // Classical GS: coefs all computed from original v[i], then one
    // subtraction pass (matches the reference's einsum structure).
#pragma unroll
    for (int i = 1; i < NM; ++i) {
        float coef[NM - 1];
#pragma unroll
        for (int k = 0; k < i; ++k) {
            coef[k] = wave_sum64(dot4(v[i], v[k]));
        }
#pragma unroll
        for (int k = 0; k < i; ++k) {
            v[i].x -= coef[k] * v[k].x;
            v[i].y -= coef[k] * v[k].y;
            v[i].z -= coef[k] * v[k].z;
            v[i].w -= coef[k] * v[k].w;
        }
        float s   = wave_sum64(dot4(v[i], v[i]));
        float inv = (s > 0.0f) ? rsqrtf(s) : 0.0f;
        v[i].x *= inv; v[i].y *= inv; v[i].z *= inv; v[i].w *= inv;
    }

    // Store (same layout as input).
#pragma unroll
    for (int i = 0; i < NM; ++i) {
        oo[(size_t)(i * NR + row) * D4 + lane] = v[i];
    }
}

extern "C" void kernel_launch(void* const* d_in, const int* in_sizes, int n_in,
                              void* d_out, int out_size, void* d_ws, size_t ws_size,
                              hipStream_t stream) {
    const float* x = (const float*)d_in[0];
    float* out     = (float*)d_out;
    // 32768 rows, 4 waves (rows) per 256-thread block.
    dim3 grid(NR / 4);
    dim3 block(256);
    hipLaunchKernelGGL(gs_kernel, grid, block, 0, stream, x, out);
}

// Round 2
// 222.707 us; speedup vs baseline: 1.3020x; 1.3020x over previous
//
#include <hip/hip_runtime.h>

// Classical Gram-Schmidt over 16 vectors of dim 256, for 32768 independent
// rows, fp32. Layout (16, 32768, 256). One wave64 per row; lane l owns
// elements [4l, 4l+4) of each vector (16 x float4 = 64 VGPRs state).
//
// R1 change: dot-product reductions use the canonical GCN wave64 DPP
// reduction (VALU-only, no ds_bpermute / lgkmcnt stalls) ending in
// v_readlane -> coefficient lives in an SGPR. Stores issued per-vector
// right after normalization to overlap writes with remaining compute.

constexpr int NM = 16;      // vectors per row
constexpr int NR = 32768;   // rows
constexpr int D4 = 64;      // 256/4 floats per lane

// One DPP-add step: x + permuted(x). Masked-out lanes get old=0 -> x+0.
template <int CTRL, int RMASK>
__device__ __forceinline__ float dpp_add(float x) {
    int xi = __builtin_bit_cast(int, x);
    int yi = __builtin_amdgcn_update_dpp(0, xi, CTRL, RMASK, 0xF, false);
    return x + __builtin_bit_cast(float, yi);
}

// Full 64-lane sum, result broadcast via SGPR (readlane 63).
__device__ __forceinline__ float wave_sum64(float x) {
    x = dpp_add<0xB1,  0xF>(x);   // quad_perm(1,0,3,2)  : pairs lane^1
    x = dpp_add<0x4E,  0xF>(x);   // quad_perm(2,3,0,1)  : pairs lane^2
    x = dpp_add<0x141, 0xF>(x);   // row_half_mirror     : pairs within 8
    x = dpp_add<0x140, 0xF>(x);   // row_mirror          : pairs within 16
    x = dpp_add<0x142, 0xA>(x);   // row_bcast15 -> rows 1,3 : 32-lane sums
    x = dpp_add<0x143, 0xC>(x);   // row_bcast31 -> rows 2,3 : lane63 = total
    int s = __builtin_amdgcn_readlane(__builtin_bit_cast(int, x), 63);
    return __builtin_bit_cast(float, s);
}

__device__ __forceinline__ float dot4(const float4& a, const float4& b) {
    return a.x * b.x + a.y * b.y + a.z * b.z + a.w * b.w;
}

__global__ __launch_bounds__(256) void gs_kernel(const float* __restrict__ x,
                                                 float* __restrict__ out) {
    const int lane = threadIdx.x & 63;
    const int wid  = threadIdx.x >> 6;
    const int row  = blockIdx.x * 4 + wid;

    const float4* __restrict__ xi = reinterpret_cast<const float4*>(x);
    float4* __restrict__ oo       = reinterpret_cast<float4*>(out);

    // Load all 16 vectors for this row (coalesced 1 KB/instruction).
    float4 v[NM];
#pragma unroll
    for (int i = 0; i < NM; ++i) {
        v[i] = xi[(size_t)(i * NR + row) * D4 + lane];
    }

    // Normalize v[0]; store immediately.
    {
        float s   = wave_sum64(dot4(v[0], v[0]));
        float inv = (s > 0.0f) ? rsqrtf(s) : 0.0f;
        v[0].x *= inv; v[0].y *= inv; v[0].z *= inv; v[0].w *= inv;
        oo[(size_t)(0 * NR + row) * D4 + lane] = v[0];
    }

    // Classical GS: all coefs from original v[i], then one subtraction pass.
#pragma unroll
    for (int i = 1; i < NM; ++i) {
        float coef[NM - 1];
#pragma unroll
        for (int k = 0; k < i; ++k) {
            coef[k] = wave_sum64(dot4(v[i], v[k]));   // SGPR-resident
        }
#pragma unroll
        for (int k = 0; k < i; ++k) {
            v[i].x -= coef[k] * v[k].x;
            v[i].y -= coef[k] * v[k].y;
            v[i].z -= coef[k] * v[k].z;
            v[i].w -= coef[k] * v[k].w;
        }
        float s   = wave_sum64(dot4(v[i], v[i]));
        float inv = (s > 0.0f) ? rsqrtf(s) : 0.0f;
        v[i].x *= inv; v[i].y *= inv; v[i].z *= inv; v[i].w *= inv;
        oo[(size_t)(i * NR + row) * D4 + lane] = v[i];
    }
}

extern "C" void kernel_launch(void* const* d_in, const int* in_sizes, int n_in,
                              void* d_out, int out_size, void* d_ws, size_t ws_size,
                              hipStream_t stream) {
    const float* x = (const float*)d_in[0];
    float* out     = (float*)d_out;
    dim3 grid(NR / 4);   // 4 waves (rows) per 256-thread block
    dim3 block(256);
    hipLaunchKernelGGL(gs_kernel, grid, block, 0, stream, x, out);
}

// Round 3
// 219.371 us; speedup vs baseline: 1.3218x; 1.0152x over previous
//
#include <hip/hip_runtime.h>

// Classical Gram-Schmidt, 16 vectors x dim-256, 32768 independent rows, fp32.
// Layout (16, 32768, 256). One wave64 per row; lane l owns elements
// [4l, 4l+4) of each vector (16 x float4 = 64 VGPRs of state).
//
// R2 changes:
//  - Block-CGS (blocks of 4): coefficient dots of vectors 4b..4b+3 against
//    the finished basis q_0..q_{4b-1} depend only on the previous block's
//    completion, not the immediately preceding norm chain -> fat independent
//    reduction phases the scheduler can overlap with the serial norm chains.
//    (Inner-block dots use the partially projected vector: MGS-style; differs
//    from the reference CGS only by the fp orthogonality defect ~1e-6.)
//  - 64-thread workgroups: the 4 waves resident per SIMD come from different
//    workgroups -> decorrelated stall phases.

constexpr int NM = 16;      // vectors per row
constexpr int NR = 32768;   // rows
constexpr int D4 = 64;      // 256/4 floats per lane

// One DPP-add step: x + permuted(x); masked-out rows receive old=0.
template <int CTRL, int RMASK>
__device__ __forceinline__ float dpp_add(float x) {
    int xi = __builtin_bit_cast(int, x);
    int yi = __builtin_amdgcn_update_dpp(0, xi, CTRL, RMASK, 0xF, false);
    return x + __builtin_bit_cast(float, yi);
}

// Full 64-lane sum; result broadcast through an SGPR (readlane 63).
__device__ __forceinline__ float wave_sum64(float x) {
    x = dpp_add<0xB1,  0xF>(x);   // quad_perm(1,0,3,2) : lane^1
    x = dpp_add<0x4E,  0xF>(x);   // quad_perm(2,3,0,1) : lane^2
    x = dpp_add<0x141, 0xF>(x);   // row_half_mirror    : within 8
    x = dpp_add<0x140, 0xF>(x);   // row_mirror         : within 16
    x = dpp_add<0x142, 0xA>(x);   // row_bcast15 -> rows 1,3
    x = dpp_add<0x143, 0xC>(x);   // row_bcast31 -> rows 2,3 ; lane63 = total
    int s = __builtin_amdgcn_readlane(__builtin_bit_cast(int, x), 63);
    return __builtin_bit_cast(float, s);
}

__device__ __forceinline__ float dot4(const float4& a, const float4& b) {
    return a.x * b.x + a.y * b.y + a.z * b.z + a.w * b.w;
}

__device__ __forceinline__ void axpy_sub(float4& y, float a, const float4& x) {
    y.x -= a * x.x; y.y -= a * x.y; y.z -= a * x.z; y.w -= a * x.w;
}

__global__ __launch_bounds__(64) void gs_kernel(const float* __restrict__ x,
                                                float* __restrict__ out) {
    const int lane = threadIdx.x;
    const int row  = blockIdx.x;

    const float4* __restrict__ xi = reinterpret_cast<const float4*>(x);
    float4* __restrict__ oo       = reinterpret_cast<float4*>(out);

    float4 v[NM];
#pragma unroll
    for (int i = 0; i < NM; ++i) {
        v[i] = xi[(size_t)(i * NR + row) * D4 + lane];
    }

    // Normalize v[i] in place (safe-div) and store it.
    auto finalize = [&](int i) {
        float s   = wave_sum64(dot4(v[i], v[i]));
        float inv = rsqrtf(s);
        inv = (s > 0.0f) ? inv : 0.0f;
        v[i].x *= inv; v[i].y *= inv; v[i].z *= inv; v[i].w *= inv;
        oo[(size_t)(i * NR + row) * D4 + lane] = v[i];
    };

    // ---- block 0: plain CGS on v[0..3] ----
    finalize(0);
#pragma unroll
    for (int i = 1; i < 4; ++i) {
        float c[3];
#pragma unroll
        for (int k = 0; k < i; ++k) c[k] = wave_sum64(dot4(v[i], v[k]));
#pragma unroll
        for (int k = 0; k < i; ++k) axpy_sub(v[i], c[k], v[k]);
        finalize(i);
    }

    // ---- blocks 1..3 ----
#pragma unroll
    for (int b = 1; b < 4; ++b) {
        const int i0 = 4 * b;
        // Fat phase: project the 4 new vectors against ALL finished basis
        // vectors q_0..q_{i0-1}. Every reduction here is independent of the
        // other new vectors' processing -> wide ILP for the scheduler.
#pragma unroll
        for (int ii = 0; ii < 4; ++ii) {
            float c[12];
#pragma unroll
            for (int k = 0; k < i0; ++k) c[k] = wave_sum64(dot4(v[i0 + ii], v[k]));
#pragma unroll
            for (int k = 0; k < i0; ++k) axpy_sub(v[i0 + ii], c[k], v[k]);
        }
        // Inner CGS within the block (the only remaining serial chain).
        finalize(i0);
#pragma unroll
        for (int ii = 1; ii < 4; ++ii) {
            float c[3];
#pragma unroll
            for (int k = 0; k < ii; ++k)
                c[k] = wave_sum64(dot4(v[i0 + ii], v[i0 + k]));
#pragma unroll
            for (int k = 0; k < ii; ++k) axpy_sub(v[i0 + ii], c[k], v[i0 + k]);
            finalize(i0 + ii);
        }
    }
}

extern "C" void kernel_launch(void* const* d_in, const int* in_sizes, int n_in,
                              void* d_out, int out_size, void* d_ws, size_t ws_size,
                              hipStream_t stream) {
    const float* x = (const float*)d_in[0];
    float* out     = (float*)d_out;
    dim3 grid(NR);      // one 64-thread workgroup (one wave) per row
    dim3 block(64);
    hipLaunchKernelGGL(gs_kernel, grid, block, 0, stream, x, out);
}